// Round 5
// baseline (924.510 us; speedup 1.0000x reference)
//
#include <hip/hip_runtime.h>

// Fused NeRF-MLP. Round 5: single LDS activation buffer (d1/d3 time-share)
// => 36.9 KB LDS => 4 blocks/CU = 4 waves/SIMD (TLP is the thesis this round).
// 4096 blocks x 256 thr (4 waves), 64 rows/block, wave = 64ch x 64rows,
// acc[4][4], in-register sigma/rgb heads, cvt_pk-only f32->bf16.

typedef __bf16 bf16x8 __attribute__((ext_vector_type(8)));
typedef float  f32x4  __attribute__((ext_vector_type(4)));
typedef float  f32x4v __attribute__((ext_vector_type(4)));
typedef short  short8 __attribute__((ext_vector_type(8)));
typedef unsigned int uint4v __attribute__((ext_vector_type(4)));

#define NROWS (8192 * 32)
#define MT 64
#define RS 264  // LDS act row stride (528 B: 4-bank row step -> ~2-way max, free)
#define SCR_OFF (MT * RS)                   // scratch offset in ushort units
#define SMEM_BYTES (MT * RS * 2 + 3072)     // 36864 B -> 4 blocks/CU

// packed-weight section offsets (bf16 elems) in d_ws
#define P0B   0        // W0^T   K=64(pad 63),  OUT=256 : 16384
#define P1B   16384    // W1     K=256, OUT=256          : 65536
#define P2B   81920    // W2     K=512, OUT=256          : 131072
#define PSB   212992   // (unused; kept for layout)      : 4096
#define P3B   217088   // W3     K=512, OUT=256          : 131072
#define P4AB  348160   // W4[:256]      K=256, OUT=256   : 65536
#define P4BB  413696   // W4[256:283]   K=32(pad 27)     : 8192
#define PRB   421888   // (unused; kept for layout)      : 4096
#define PTOT  425984

__device__ __forceinline__ unsigned short f2bf(float f) {
  unsigned u = __builtin_bit_cast(unsigned, f);
  u += 0x7fffu + ((u >> 16) & 1u);   // RNE
  return (unsigned short)(u >> 16);
}
__device__ __forceinline__ unsigned cvt_pk(float lo, float hi) {
  unsigned r;
  asm("v_cvt_pk_bf16_f32 %0, %1, %2" : "=v"(r) : "v"(lo), "v"(hi));
  return r;
}
// 8 f32 -> bf16x8 via 4 cvt_pk, no shift/pack ops
__device__ __forceinline__ bf16x8 cvt8(f32x4v x, f32x4v y) {
  uint4v u;
  u[0] = cvt_pk(x[0], x[1]); u[1] = cvt_pk(x[2], x[3]);
  u[2] = cvt_pk(y[0], y[1]); u[3] = cvt_pk(y[2], y[3]);
  return __builtin_bit_cast(bf16x8, u);
}
__device__ __forceinline__ bf16x8 as_bf(short8 s) {
  return __builtin_bit_cast(bf16x8, s);
}

// ---------------- pre-pass: pack weights to bf16 fragment layout ------------
// pack[((kt*OUTP + o)*4 + seg)*8 + j] = W[kt*32 + seg*8 + j][o]
__global__ void prep_pack(const float* __restrict__ W0, const float* __restrict__ W1,
                          const float* __restrict__ W2, const float* __restrict__ Ws,
                          const float* __restrict__ W3, const float* __restrict__ W4,
                          const float* __restrict__ Wr, const float* __restrict__ app,
                          const float* __restrict__ b4,
                          unsigned short* __restrict__ pack, float* __restrict__ b4p,
                          float* __restrict__ wrT)
{
  int gid = blockIdx.x * 256 + threadIdx.x;
  if (gid < PTOT) {
    const float* W; int OUTP, OUTR, Kreal, base, krow = 0;
    if      (gid < P1B)  { W = W0; OUTP = 256; OUTR = 256; Kreal = 63;  base = P0B; }
    else if (gid < P2B)  { W = W1; OUTP = 256; OUTR = 256; Kreal = 256; base = P1B; }
    else if (gid < PSB)  { W = W2; OUTP = 256; OUTR = 256; Kreal = 512; base = P2B; }
    else if (gid < P3B)  { W = Ws; OUTP = 16;  OUTR = 1;   Kreal = 256; base = PSB; }
    else if (gid < P4AB) { W = W3; OUTP = 256; OUTR = 256; Kreal = 512; base = P3B; }
    else if (gid < P4BB) { W = W4; OUTP = 256; OUTR = 256; Kreal = 256; base = P4AB; }
    else if (gid < PRB)  { W = W4; OUTP = 256; OUTR = 256; Kreal = 27;  base = P4BB; krow = 256; }
    else                 { W = Wr; OUTP = 16;  OUTR = 3;   Kreal = 256; base = PRB; }
    int local = gid - base;
    int j   = local & 7;
    int seg = (local >> 3) & 3;
    int rest = local >> 5;
    int o  = rest & (OUTP - 1);
    int kt = rest >> ((OUTP == 256) ? 8 : 4);
    int k  = kt * 32 + seg * 8 + j;
    float v = 0.f;
    if (k < Kreal && o < OUTR) v = W[(long)(k + krow) * OUTR + o];
    pack[gid] = f2bf(v);
  } else if (gid < PTOT + 256) {
    int o = gid - PTOT;
    float a = b4[o];
    for (int i = 0; i < 48; ++i) a += app[i] * W4[(long)(283 + i) * 256 + o];
    b4p[o] = a;
  } else if (gid < PTOT + 256 + 768) {
    int idx = gid - (PTOT + 256);
    int c = idx >> 8, ch = idx & 255;
    wrT[c * 256 + ch] = Wr[ch * 3 + c];
  }
}

// ---------------- main fused kernel ----------------------------------------
__global__ __launch_bounds__(256, 4)
void nerf_fused(const float* __restrict__ pos, const float* __restrict__ dirs,
                const float* __restrict__ gemo, const float* __restrict__ color,
                const float* __restrict__ mask,
                const unsigned short* __restrict__ wp,
                const float* __restrict__ b0, const float* __restrict__ b1,
                const float* __restrict__ b2, const float* __restrict__ bsv,
                const float* __restrict__ b3, const float* __restrict__ b4p,
                const float* __restrict__ brv,
                const float* __restrict__ Wsf, const float* __restrict__ wrT,
                float* __restrict__ osig, float* __restrict__ orgb)
{
  extern __shared__ unsigned short smem[];
  unsigned short* buf0 = smem;            // [64][RS] -- d0, then d1, then d3
  float* scr = (float*)(smem + SCR_OFF);  // 3072 B head-reduce scratch

  const int tid  = (int)threadIdx.x;
  const int w    = tid >> 6;
  const int lane = tid & 63;
  const int l16  = lane & 15;
  const int seg  = lane >> 4;
  const int chb  = w * 64;              // 4 disjoint 64-ch slices
  const long R0  = (long)blockIdx.x * MT;
  const int rot  = (int)(blockIdx.x & 7);

  f32x4 acc[4][4];

  auto ldA = [&](int baseElems, int o, int kt) -> bf16x8 {
    const bf16x8* p = (const bf16x8*)(wp + baseElems);
    return p[(kt * 256 + o) * 4 + seg];
  };
  auto ldB_lds = [&](const unsigned short* buf, int rt, int kt) -> bf16x8 {
    int row = rt * 16 + l16;
    return *(const bf16x8*)(buf + row * RS + kt * 32 + seg * 8);
  };
  auto ldB_gen = [&](const float* __restrict__ p, int stride, int Kreal,
                     int rt, int ktl) -> bf16x8 {
    long row = R0 + rt * 16 + l16;
    const float* q = p + row * stride;
    int k0 = ktl * 32 + seg * 8;
    short8 s;
#pragma unroll
    for (int j = 0; j < 8; ++j) {
      float v = (k0 + j < Kreal) ? __builtin_nontemporal_load(q + k0 + j) : 0.0f;
      s[j] = (short)f2bf(v);
    }
    return as_bf(s);
  };
  auto initAcc = [&](const float* __restrict__ b) {
#pragma unroll
    for (int ct = 0; ct < 4; ++ct) {
      float4 bv = *(const float4*)(b + chb + ct * 16 + seg * 4);
      f32x4 t; t[0] = bv.x; t[1] = bv.y; t[2] = bv.z; t[3] = bv.w;
#pragma unroll
      for (int rt = 0; rt < 4; ++rt) acc[ct][rt] = t;
    }
  };
  auto storeAct = [&](unsigned short* __restrict__ buf) {
#pragma unroll
    for (int ct = 0; ct < 4; ++ct)
#pragma unroll
      for (int rt = 0; rt < 4; ++rt) {
        int row = rt * 16 + l16;
        int ch  = chb + ct * 16 + seg * 4;
        f32x4 v = acc[ct][rt];
        uint2 u;
        u.x = cvt_pk(fmaxf(v[0], 0.f), fmaxf(v[1], 0.f));
        u.y = cvt_pk(fmaxf(v[2], 0.f), fmaxf(v[3], 0.f));
        *(uint2*)(buf + row * RS + ch) = u;  // ds_write_b64
      }
  };

// one K32 step: 4 B-frags + 4 A-loads -> 16 MFMA
#define GSTEP(ABASE, kt, BLOADER)                                              \
  {                                                                            \
    bf16x8 Bf[4];                                                              \
    _Pragma("unroll") for (int rt = 0; rt < 4; ++rt) Bf[rt] = BLOADER;         \
    _Pragma("unroll") for (int ct = 0; ct < 4; ++ct) {                         \
      bf16x8 Af = ldA(ABASE, chb + ct * 16 + l16, kt);                         \
      _Pragma("unroll") for (int rt = 0; rt < 4; ++rt)                         \
        acc[ct][rt] = __builtin_amdgcn_mfma_f32_16x16x32_bf16(                 \
            Af, Bf[rt], acc[ct][rt], 0, 0, 0);                                 \
    }                                                                          \
  }

// 8-step half, B from LDS
#define LHALF(ABASE, BUF)                                                      \
  _Pragma("unroll") for (int i = 0; i < 8; ++i) {                              \
    int kt = (i + rot) & 7;                                                    \
    GSTEP(ABASE, kt, ldB_lds(BUF, rt, kt));                                    \
  }

// 8-step half, B streamed NT from global f32 [N,256], distance-1 prefetch
#define GHALF(ABASE, P)                                                        \
  {                                                                            \
    f32x4v pre[4][2];                                                          \
    {                                                                          \
      int ktl0 = rot & 7;                                                      \
      _Pragma("unroll") for (int rt = 0; rt < 4; ++rt) {                       \
        const f32x4v* q = (const f32x4v*)((P) + (R0 + rt * 16 + l16) * 256 +   \
                                          ktl0 * 32 + seg * 8);                \
        pre[rt][0] = __builtin_nontemporal_load(q);                            \
        pre[rt][1] = __builtin_nontemporal_load(q + 1);                        \
      }                                                                        \
    }                                                                          \
    _Pragma("unroll") for (int i = 0; i < 8; ++i) {                            \
      bf16x8 Bf[4];                                                            \
      _Pragma("unroll") for (int rt = 0; rt < 4; ++rt)                         \
        Bf[rt] = cvt8(pre[rt][0], pre[rt][1]);                                 \
      if (i + 1 < 8) {                                                         \
        int ktl = (i + 1 + rot) & 7;                                           \
        _Pragma("unroll") for (int rt = 0; rt < 4; ++rt) {                     \
          const f32x4v* q = (const f32x4v*)((P) + (R0 + rt * 16 + l16) * 256 + \
                                            ktl * 32 + seg * 8);               \
          pre[rt][0] = __builtin_nontemporal_load(q);                          \
          pre[rt][1] = __builtin_nontemporal_load(q + 1);                      \
        }                                                                      \
      }                                                                        \
      int kt = 8 + ((i + rot) & 7);                                            \
      _Pragma("unroll") for (int ct = 0; ct < 4; ++ct) {                       \
        bf16x8 Af = ldA(ABASE, chb + ct * 16 + l16, kt);                       \
        _Pragma("unroll") for (int rt = 0; rt < 4; ++rt)                       \
          acc[ct][rt] = __builtin_amdgcn_mfma_f32_16x16x32_bf16(               \
              Af, Bf[rt], acc[ct][rt], 0, 0, 0);                               \
      }                                                                        \
    }                                                                          \
  }

  // ---- L0: d0 = relu(pos @ W0 + b0) -> buf0
  initAcc(b0);
  GSTEP(P0B, 0, ldB_gen(pos, 63, 63, rt, 0));
  GSTEP(P0B, 1, ldB_gen(pos, 63, 63, rt, 1));
  storeAct(buf0);
  __syncthreads();

  // ---- L1: d1 = relu(d0 @ W1 + b1); buf0: d0 -> d1 (barrier-separated)
  initAcc(b1);
  LHALF(P1B, buf0);
  __syncthreads();          // all reads of d0 done
  storeAct(buf0);
  __syncthreads();          // d1 ready

  // ---- L2: d2 = [d1|gemo] @ W2 + b2 (pre-relu in acc; never stored)
  initAcc(b2);
  GHALF(P2B, gemo);
  LHALF(P2B, buf0);

  // ---- sigma head (in-register): softplus(relu(d2) @ Ws + bs) * mask
  {
    float p[4];
#pragma unroll
    for (int rt = 0; rt < 4; ++rt) {
      float s = 0.f;
#pragma unroll
      for (int ct = 0; ct < 4; ++ct) {
        float4 w4 = *(const float4*)(Wsf + chb + ct * 16 + seg * 4);
        f32x4 a = acc[ct][rt];
        s += fmaxf(a[0], 0.f) * w4.x + fmaxf(a[1], 0.f) * w4.y +
             fmaxf(a[2], 0.f) * w4.z + fmaxf(a[3], 0.f) * w4.w;
      }
      s += __shfl_xor(s, 16);
      s += __shfl_xor(s, 32);
      p[rt] = s;
    }
    if (seg == 0) {
#pragma unroll
      for (int rt = 0; rt < 4; ++rt) scr[w * 64 + rt * 16 + l16] = p[rt];
    }
  }
  __syncthreads();
  if (tid < 64) {
    float s = scr[tid] + scr[64 + tid] + scr[128 + tid] + scr[192 + tid] + bsv[0];
    float sp = fmaxf(s, 0.f) + log1pf(expf(-fabsf(s)));
    float m = __builtin_nontemporal_load(mask + R0 + tid);
    __builtin_nontemporal_store(sp * m, osig + R0 + tid);
  }

  // ---- L3: d3 = relu([d1|color] @ W3 + b3); buf0: d1 -> d3
  initAcc(b3);
  GHALF(P3B, color);
  LHALF(P3B, buf0);
  __syncthreads();          // all reads of d1 done (incl. sigma scr reads)
  storeAct(buf0);
  __syncthreads();          // d3 ready

  // ---- L4: d4 = [d3|dir|app] @ W4 + b4' (pre-relu in acc; never stored)
  initAcc(b4p);
  GSTEP(P4BB, 0, ldB_gen(dirs, 27, 27, rt, 0));
  LHALF(P4AB, buf0);

  // ---- rgb head (in-register): sigmoid(relu(d4) @ Wr + br)
  {
#pragma unroll
    for (int ct = 0; ct < 4; ++ct)
#pragma unroll
      for (int rt = 0; rt < 4; ++rt) {
        f32x4 a = acc[ct][rt];
        a[0] = fmaxf(a[0], 0.f); a[1] = fmaxf(a[1], 0.f);
        a[2] = fmaxf(a[2], 0.f); a[3] = fmaxf(a[3], 0.f);
        acc[ct][rt] = a;
      }
#pragma unroll
    for (int c = 0; c < 3; ++c) {
      float p[4];
#pragma unroll
      for (int rt = 0; rt < 4; ++rt) {
        float s = 0.f;
#pragma unroll
        for (int ct = 0; ct < 4; ++ct) {
          float4 w4 = *(const float4*)(wrT + c * 256 + chb + ct * 16 + seg * 4);
          f32x4 a = acc[ct][rt];
          s += a[0] * w4.x + a[1] * w4.y + a[2] * w4.z + a[3] * w4.w;
        }
        s += __shfl_xor(s, 16);
        s += __shfl_xor(s, 32);
        p[rt] = s;
      }
      if (seg == 0) {
#pragma unroll
        for (int rt = 0; rt < 4; ++rt)
          scr[c * 256 + w * 64 + rt * 16 + l16] = p[rt];
      }
    }
  }
  __syncthreads();
  if (tid < 64) {
#pragma unroll
    for (int c = 0; c < 3; ++c) {
      float s = scr[c * 256 + tid] + scr[c * 256 + 64 + tid] +
                scr[c * 256 + 128 + tid] + scr[c * 256 + 192 + tid] + brv[c];
      float r = 1.f / (1.f + expf(-s));
      __builtin_nontemporal_store(r, orgb + (R0 + tid) * 3 + c);
    }
  }
#undef GSTEP
#undef LHALF
#undef GHALF
}

extern "C" void kernel_launch(void* const* d_in, const int* in_sizes, int n_in,
                              void* d_out, int out_size, void* d_ws, size_t ws_size,
                              hipStream_t stream) {
  const float* pos   = (const float*)d_in[0];
  const float* dirs  = (const float*)d_in[1];
  const float* app   = (const float*)d_in[2];
  const float* gemo  = (const float*)d_in[3];
  const float* color = (const float*)d_in[4];
  const float* mask  = (const float*)d_in[5];
  // d_in[6] = num_inters (fixed 32, shapes are static)
  const float* W0 = (const float*)d_in[7];   const float* b0 = (const float*)d_in[8];
  const float* W1 = (const float*)d_in[9];   const float* b1 = (const float*)d_in[10];
  const float* W2 = (const float*)d_in[11];  const float* b2 = (const float*)d_in[12];
  const float* Ws = (const float*)d_in[13];  const float* bs = (const float*)d_in[14];
  const float* W3 = (const float*)d_in[15];  const float* b3 = (const float*)d_in[16];
  const float* W4 = (const float*)d_in[17];  const float* b4 = (const float*)d_in[18];
  const float* Wr = (const float*)d_in[19];  const float* br = (const float*)d_in[20];

  unsigned short* pack = (unsigned short*)d_ws;
  float* b4p = (float*)((char*)d_ws + (size_t)PTOT * 2);
  float* wrT = b4p + 256;

  float* osig = (float*)d_out;
  float* orgb = osig + NROWS;

  prep_pack<<<dim3((PTOT + 256 + 768 + 255) / 256), dim3(256), 0, stream>>>(
      W0, W1, W2, Ws, W3, W4, Wr, app, b4, pack, b4p, wrT);

  hipFuncSetAttribute((const void*)nerf_fused,
                      hipFuncAttributeMaxDynamicSharedMemorySize, SMEM_BYTES);

  nerf_fused<<<dim3(NROWS / MT), dim3(256), SMEM_BYTES, stream>>>(
      pos, dirs, gemo, color, mask, pack,
      b0, b1, b2, bs, b3, b4p, br, Ws, wrT, osig, orgb);
}

// Round 6
// 588.922 us; speedup vs baseline: 1.5698x; 1.5698x over previous
//
#include <hip/hip_runtime.h>

// Fused NeRF-MLP. Round 6: T3/T4-style per-wave weight staging.
// Each K32-step's weights = contiguous 16KB chunk; wave w async-stages its
// own 4KB slice via 4x global_load_lds into a double-buffered LDS stage.
// Counted s_waitcnt vmcnt(N) + sched_barrier(0) fences keep next-step stage
// (and distance-2 gemo/color register prefetch) in flight across each step.
// No barriers in the K-loop (stage slices are wave-private).
// 4096 blocks x 256 thr (4 waves), 64 rows/block, wave = 64ch x 64rows.

typedef __bf16 bf16x8 __attribute__((ext_vector_type(8)));
typedef float  f32x4  __attribute__((ext_vector_type(4)));
typedef short  short8 __attribute__((ext_vector_type(8)));
typedef unsigned int uint4v __attribute__((ext_vector_type(4)));

#define NROWS (8192 * 32)
#define MT 64

// packed-weight section offsets (bf16 elems); every kt is a contiguous
// 8192-elem (16KB) chunk laid out so each wave's A-reads are lane-linear.
#define P0B   0        // W0^T  K=64 (pad 63)  : 2 kt
#define P1B   16384    // W1    K=256          : 8 kt
#define P2B   81920    // W2    K=512          : 16 kt
#define P3B   212992   // W3    K=512          : 16 kt
#define P4AB  344064   // W4[:256]   K=256     : 8 kt
#define P4BB  409600   // W4[256:283] K=32(27) : 1 kt
#define PTOT  417792

#define ACT_ELEMS (64 * 256)            // 32 KB, XOR-swizzled
#define SMEM_BYTES (ACT_ELEMS * 2 + 2 * 8192 * 2 + 3072)  // 68608 -> 2 blk/CU

__device__ __forceinline__ unsigned short f2bf(float f) {
  unsigned u = __builtin_bit_cast(unsigned, f);
  u += 0x7fffu + ((u >> 16) & 1u);   // RNE
  return (unsigned short)(u >> 16);
}
__device__ __forceinline__ unsigned cvt_pk(float lo, float hi) {
  unsigned r;
  asm("v_cvt_pk_bf16_f32 %0, %1, %2" : "=v"(r) : "v"(lo), "v"(hi));
  return r;
}
__device__ __forceinline__ bf16x8 cvt8(f32x4 x, f32x4 y) {
  uint4v u;
  u[0] = cvt_pk(x[0], x[1]); u[1] = cvt_pk(x[2], x[3]);
  u[2] = cvt_pk(y[0], y[1]); u[3] = cvt_pk(y[2], y[3]);
  return __builtin_bit_cast(bf16x8, u);
}
__device__ __forceinline__ bf16x8 as_bf(short8 s) {
  return __builtin_bit_cast(bf16x8, s);
}

#define SB __builtin_amdgcn_sched_barrier(0)
#define FENCE(n) do { asm volatile("s_waitcnt vmcnt(" #n ")" ::: "memory"); SB; } while (0)

#define GLDS16(gsrc, ldst)                                                     \
  __builtin_amdgcn_global_load_lds(                                            \
      (const __attribute__((address_space(1))) unsigned int*)(gsrc),           \
      (__attribute__((address_space(3))) unsigned int*)(ldst), 16, 0, 0)

// ---------------- pre-pass: pack weights to staged fragment layout ----------
// chunk(kt) elem index bits: wv[12:11] ct[10:9] seg[8:7] l16[6:3] j[2:0]
// holds W[kt*32 + seg*8 + j][wv*64 + ct*16 + l16]
__global__ void prep_pack(const float* __restrict__ W0, const float* __restrict__ W1,
                          const float* __restrict__ W2, const float* __restrict__ W3,
                          const float* __restrict__ W4, const float* __restrict__ Wr,
                          const float* __restrict__ app, const float* __restrict__ b4,
                          unsigned short* __restrict__ pack, float* __restrict__ b4p,
                          float* __restrict__ wrT)
{
  int gid = blockIdx.x * 256 + threadIdx.x;
  if (gid < PTOT) {
    const float* W; int Kreal, base, krow = 0;
    if      (gid < P1B)  { W = W0; Kreal = 63;  base = P0B; }
    else if (gid < P2B)  { W = W1; Kreal = 256; base = P1B; }
    else if (gid < P3B)  { W = W2; Kreal = 512; base = P2B; }
    else if (gid < P4AB) { W = W3; Kreal = 512; base = P3B; }
    else if (gid < P4BB) { W = W4; Kreal = 256; base = P4AB; }
    else                 { W = W4; Kreal = 27;  base = P4BB; krow = 256; }
    int local = gid - base;
    int j   = local & 7;
    int l16 = (local >> 3) & 15;
    int seg = (local >> 7) & 3;
    int ct  = (local >> 9) & 3;
    int wv  = (local >> 11) & 3;
    int kt  = local >> 13;
    int o = wv * 64 + ct * 16 + l16;
    int k = kt * 32 + seg * 8 + j;
    float v = (k < Kreal) ? W[(long)(k + krow) * 256 + o] : 0.f;
    pack[gid] = f2bf(v);
  } else if (gid < PTOT + 256) {
    int o = gid - PTOT;
    float a = b4[o];
    for (int i = 0; i < 48; ++i) a += app[i] * W4[(long)(283 + i) * 256 + o];
    b4p[o] = a;
  } else if (gid < PTOT + 256 + 768) {
    int idx = gid - (PTOT + 256);
    int c = idx >> 8, ch = idx & 255;
    wrT[c * 256 + ch] = Wr[ch * 3 + c];
  }
}

// ---------------- main fused kernel ----------------------------------------
__global__ __launch_bounds__(256, 2)
void nerf_fused(const float* __restrict__ pos, const float* __restrict__ dirs,
                const float* __restrict__ gemo, const float* __restrict__ color,
                const float* __restrict__ mask,
                const unsigned short* __restrict__ wp,
                const float* __restrict__ b0, const float* __restrict__ b1,
                const float* __restrict__ b2, const float* __restrict__ bsv,
                const float* __restrict__ b3, const float* __restrict__ b4p,
                const float* __restrict__ brv,
                const float* __restrict__ Wsf, const float* __restrict__ wrT,
                float* __restrict__ osig, float* __restrict__ orgb)
{
  extern __shared__ unsigned short smem[];
  unsigned short* act = smem;                    // [64][256] XOR-swizzled
  unsigned short* wst = smem + ACT_ELEMS;        // [2][8192] weight stage
  float* scr = (float*)(smem + ACT_ELEMS + 2 * 8192);  // 3 KB head scratch

  const int tid  = (int)threadIdx.x;
  const int w    = tid >> 6;
  const int lane = tid & 63;
  const int l16  = lane & 15;
  const int seg  = lane >> 4;
  const int chb  = w * 64;              // 4 disjoint 64-ch slices
  const long R0  = (long)blockIdx.x * MT;
  const int rot  = (int)(blockIdx.x & 7);

  f32x4 acc[4][4];

// stage one kt chunk: wave w's 2048-elem slice, 4x global_load_lds(16B)
#define STAGE(b, ABASE, kt)                                                    \
  {                                                                            \
    const unsigned short* s_ = wp + (ABASE) + (kt) * 8192 + w * 2048 + lane * 8; \
    unsigned short* d_ = wst + (b) * 8192 + w * 2048;                          \
    GLDS16(s_,        d_);                                                     \
    GLDS16(s_ + 512,  d_ + 512);                                               \
    GLDS16(s_ + 1024, d_ + 1024);                                              \
    GLDS16(s_ + 1536, d_ + 1536);                                              \
  }

  // A-fragment from stage buffer b: lane-linear 16B reads (conflict-free)
  auto ldAs = [&](int b, int ct) -> bf16x8 {
    return *(const bf16x8*)(wst + b * 8192 + w * 2048 +
                            ((ct * 4 + seg) * 16 + l16) * 8);
  };
  // A-fragment direct from global (L0 / dir-step only)
  auto ldAd = [&](int baseElems, int kt, int ct) -> bf16x8 {
    return *(const bf16x8*)(wp + baseElems + kt * 8192 + w * 2048 +
                            ((ct * 4 + seg) * 16 + l16) * 8);
  };
  // act buffer: elem (row,col) at row*256 + ((col>>3 ^ (row&7))<<3) + (col&7)
  auto ldB_act = [&](int rt, int kt) -> bf16x8 {
    int row = rt * 16 + l16;
    int unit = (kt * 4 + seg) ^ (row & 7);
    return *(const bf16x8*)(act + row * 256 + (unit << 3));
  };
  auto ldB_gen = [&](const float* __restrict__ p, int stride, int Kreal,
                     int rt, int ktl) -> bf16x8 {
    long row = R0 + rt * 16 + l16;
    const float* q = p + row * stride;
    int k0 = ktl * 32 + seg * 8;
    short8 s;
#pragma unroll
    for (int j = 0; j < 8; ++j) {
      float v = (k0 + j < Kreal) ? __builtin_nontemporal_load(q + k0 + j) : 0.0f;
      s[j] = (short)f2bf(v);
    }
    return as_bf(s);
  };
  auto initAcc = [&](const float* __restrict__ b) {
#pragma unroll
    for (int ct = 0; ct < 4; ++ct) {
      float4 bv = *(const float4*)(b + chb + ct * 16 + seg * 4);
      f32x4 t; t[0] = bv.x; t[1] = bv.y; t[2] = bv.z; t[3] = bv.w;
#pragma unroll
      for (int rt = 0; rt < 4; ++rt) acc[ct][rt] = t;
    }
  };
  auto storeAct = [&]() {
#pragma unroll
    for (int ct = 0; ct < 4; ++ct)
#pragma unroll
      for (int rt = 0; rt < 4; ++rt) {
        int row = rt * 16 + l16;
        int col = chb + ct * 16 + seg * 4;
        int unit = (col >> 3) ^ (row & 7);
        f32x4 v = acc[ct][rt];
        uint2 u;
        u.x = cvt_pk(fmaxf(v[0], 0.f), fmaxf(v[1], 0.f));
        u.y = cvt_pk(fmaxf(v[2], 0.f), fmaxf(v[3], 0.f));
        *(uint2*)(act + row * 256 + (unit << 3) + (col & 7)) = u;
      }
  };

#define MFMA16(AEXPR, BFRAGS)                                                  \
  _Pragma("unroll") for (int ct = 0; ct < 4; ++ct) {                           \
    bf16x8 Af_ = (AEXPR);                                                      \
    _Pragma("unroll") for (int rt = 0; rt < 4; ++rt)                           \
      acc[ct][rt] = __builtin_amdgcn_mfma_f32_16x16x32_bf16(                   \
          Af_, BFRAGS[rt], acc[ct][rt], 0, 0, 0);                              \
  }

#define BLOAD(slot, P, ktl)                                                    \
  _Pragma("unroll") for (int rt = 0; rt < 4; ++rt) {                           \
    const f32x4* q_ = (const f32x4*)((P) + (R0 + rt * 16 + l16) * 256 +        \
                                     (ktl) * 32 + seg * 8);                    \
    pre[slot][rt][0] = __builtin_nontemporal_load(q_);                         \
    pre[slot][rt][1] = __builtin_nontemporal_load(q_ + 1);                     \
  }

// 8 staged steps, B from act LDS. PROLOG=1: stage own kt0 (else chained).
#define LHALF(ABASE, PROLOG)                                                   \
  {                                                                            \
    if (PROLOG) { SB; STAGE(0, ABASE, rot & 7); }                              \
    _Pragma("unroll") for (int i = 0; i < 8; ++i) {                            \
      SB;                                                                      \
      if (i < 7) { STAGE((i + 1) & 1, ABASE, (i + 1 + rot) & 7); FENCE(4); }   \
      else FENCE(0);                                                           \
      int kt_ = (i + rot) & 7;                                                 \
      bf16x8 Bf_[4];                                                           \
      _Pragma("unroll") for (int rt = 0; rt < 4; ++rt)                         \
        Bf_[rt] = ldB_act(rt, kt_);                                            \
      MFMA16(ldAs(i & 1, ct), Bf_);                                            \
    }                                                                          \
  }

// 8 staged steps, B streamed NT from global f32 [N,256], distance-2 prefetch.
// CHAIN=1: last region stages following LHALF's kt0 into buf0.
#define GHALF(ABASE, P, CHAIN)                                                 \
  {                                                                            \
    f32x4 pre[2][4][2];                                                        \
    SB;                                                                        \
    STAGE(0, ABASE, 8 + (rot & 7));                                            \
    BLOAD(0, P, rot & 7);                                                      \
    BLOAD(1, P, (1 + rot) & 7);                                                \
    _Pragma("unroll") for (int i = 0; i < 8; ++i) {                            \
      SB;                                                                      \
      if (i < 7) { STAGE((i + 1) & 1, ABASE, 8 + ((i + 1 + rot) & 7)); FENCE(12); } \
      else if (CHAIN) { STAGE(0, ABASE, rot & 7); FENCE(4); }                  \
      else FENCE(0);                                                           \
      bf16x8 Bf_[4];                                                           \
      _Pragma("unroll") for (int rt = 0; rt < 4; ++rt)                         \
        Bf_[rt] = cvt8(pre[i & 1][rt][0], pre[i & 1][rt][1]);                  \
      if (i < 6) BLOAD(i & 1, P, (i + 2 + rot) & 7);                           \
      MFMA16(ldAs(i & 1, ct), Bf_);                                            \
    }                                                                          \
  }

  // ---- L0: d0 = relu(pos @ W0 + b0) -> act
  initAcc(b0);
#pragma unroll
  for (int kt = 0; kt < 2; ++kt) {
    bf16x8 Bf_[4];
#pragma unroll
    for (int rt = 0; rt < 4; ++rt) Bf_[rt] = ldB_gen(pos, 63, 63, rt, kt);
    MFMA16(ldAd(P0B, kt, ct), Bf_);
  }
  storeAct();
  __syncthreads();

  // ---- L1: d1 = relu(d0 @ W1 + b1); act: d0 -> d1
  initAcc(b1);
  LHALF(P1B, 1);
  __syncthreads();
  storeAct();
  __syncthreads();

  // ---- L2: d2 = [d1|gemo] @ W2 + b2 (stays in acc)
  initAcc(b2);
  GHALF(P2B, gemo, 1);
  LHALF(P2B, 0);

  // ---- sigma head (in-register): softplus(relu(d2) @ Ws + bs) * mask
  {
    float p[4];
#pragma unroll
    for (int rt = 0; rt < 4; ++rt) {
      float s = 0.f;
#pragma unroll
      for (int ct = 0; ct < 4; ++ct) {
        float4 w4 = *(const float4*)(Wsf + chb + ct * 16 + seg * 4);
        f32x4 a = acc[ct][rt];
        s += fmaxf(a[0], 0.f) * w4.x + fmaxf(a[1], 0.f) * w4.y +
             fmaxf(a[2], 0.f) * w4.z + fmaxf(a[3], 0.f) * w4.w;
      }
      s += __shfl_xor(s, 16);
      s += __shfl_xor(s, 32);
      p[rt] = s;
    }
    if (seg == 0) {
#pragma unroll
      for (int rt = 0; rt < 4; ++rt) scr[w * 64 + rt * 16 + l16] = p[rt];
    }
  }
  __syncthreads();
  if (tid < 64) {
    float s = scr[tid] + scr[64 + tid] + scr[128 + tid] + scr[192 + tid] + bsv[0];
    float sp = fmaxf(s, 0.f) + log1pf(expf(-fabsf(s)));
    float m = __builtin_nontemporal_load(mask + R0 + tid);
    __builtin_nontemporal_store(sp * m, osig + R0 + tid);
  }

  // ---- L3: d3 = relu([d1|color] @ W3 + b3); act: d1 -> d3
  initAcc(b3);
  GHALF(P3B, color, 1);
  LHALF(P3B, 0);
  __syncthreads();
  storeAct();
  __syncthreads();

  // ---- L4: d4 = [d3|dir|app] @ W4 + b4' (stays in acc)
  initAcc(b4p);
  LHALF(P4AB, 1);
  {  // dir step (K=32, direct A)
    bf16x8 Bf_[4];
#pragma unroll
    for (int rt = 0; rt < 4; ++rt) Bf_[rt] = ldB_gen(dirs, 27, 27, rt, 0);
    MFMA16(ldAd(P4BB, 0, ct), Bf_);
  }

  // ---- rgb head (in-register): sigmoid(relu(d4) @ Wr + br)
  {
#pragma unroll
    for (int ct = 0; ct < 4; ++ct)
#pragma unroll
      for (int rt = 0; rt < 4; ++rt) {
        f32x4 a = acc[ct][rt];
        a[0] = fmaxf(a[0], 0.f); a[1] = fmaxf(a[1], 0.f);
        a[2] = fmaxf(a[2], 0.f); a[3] = fmaxf(a[3], 0.f);
        acc[ct][rt] = a;
      }
#pragma unroll
    for (int c = 0; c < 3; ++c) {
      float p[4];
#pragma unroll
      for (int rt = 0; rt < 4; ++rt) {
        float s = 0.f;
#pragma unroll
        for (int ct = 0; ct < 4; ++ct) {
          float4 w4 = *(const float4*)(wrT + c * 256 + chb + ct * 16 + seg * 4);
          f32x4 a = acc[ct][rt];
          s += a[0] * w4.x + a[1] * w4.y + a[2] * w4.z + a[3] * w4.w;
        }
        s += __shfl_xor(s, 16);
        s += __shfl_xor(s, 32);
        p[rt] = s;
      }
      if (seg == 0) {
#pragma unroll
        for (int rt = 0; rt < 4; ++rt)
          scr[c * 256 + w * 64 + rt * 16 + l16] = p[rt];
      }
    }
  }
  __syncthreads();
  if (tid < 64) {
#pragma unroll
    for (int c = 0; c < 3; ++c) {
      float s = scr[c * 256 + tid] + scr[c * 256 + 64 + tid] +
                scr[c * 256 + 128 + tid] + scr[c * 256 + 192 + tid] + brv[c];
      float r = 1.f / (1.f + expf(-s));
      __builtin_nontemporal_store(r, orgb + (R0 + tid) * 3 + c);
    }
  }
#undef STAGE
#undef MFMA16
#undef BLOAD
#undef LHALF
#undef GHALF
}

extern "C" void kernel_launch(void* const* d_in, const int* in_sizes, int n_in,
                              void* d_out, int out_size, void* d_ws, size_t ws_size,
                              hipStream_t stream) {
  const float* pos   = (const float*)d_in[0];
  const float* dirs  = (const float*)d_in[1];
  const float* app   = (const float*)d_in[2];
  const float* gemo  = (const float*)d_in[3];
  const float* color = (const float*)d_in[4];
  const float* mask  = (const float*)d_in[5];
  // d_in[6] = num_inters (fixed 32, shapes are static)
  const float* W0 = (const float*)d_in[7];   const float* b0 = (const float*)d_in[8];
  const float* W1 = (const float*)d_in[9];   const float* b1 = (const float*)d_in[10];
  const float* W2 = (const float*)d_in[11];  const float* b2 = (const float*)d_in[12];
  const float* Ws = (const float*)d_in[13];  const float* bs = (const float*)d_in[14];
  const float* W3 = (const float*)d_in[15];  const float* b3 = (const float*)d_in[16];
  const float* W4 = (const float*)d_in[17];  const float* b4 = (const float*)d_in[18];
  const float* Wr = (const float*)d_in[19];  const float* br = (const float*)d_in[20];

  unsigned short* pack = (unsigned short*)d_ws;
  float* b4p = (float*)((char*)d_ws + (size_t)PTOT * 2);
  float* wrT = b4p + 256;

  float* osig = (float*)d_out;
  float* orgb = osig + NROWS;

  prep_pack<<<dim3((PTOT + 256 + 768 + 255) / 256), dim3(256), 0, stream>>>(
      W0, W1, W2, W3, W4, Wr, app, b4, pack, b4p, wrT);

  hipFuncSetAttribute((const void*)nerf_fused,
                      hipFuncAttributeMaxDynamicSharedMemorySize, SMEM_BYTES);

  nerf_fused<<<dim3(NROWS / MT), dim3(256), SMEM_BYTES, stream>>>(
      pos, dirs, gemo, color, mask, pack,
      b0, b1, b2, bs, b3, b4p, br, Ws, wrT, osig, orgb);
}